// Round 10
// baseline (486.987 us; speedup 1.0000x reference)
//
#include <hip/hip_runtime.h>
#include <hip/hip_bf16.h>

typedef unsigned short u16;
typedef unsigned int   u32;
typedef __bf16 bf16x8 __attribute__((ext_vector_type(8)));
typedef float  f32x4  __attribute__((ext_vector_type(4)));
typedef float  f32x4v __attribute__((ext_vector_type(4)));
typedef unsigned short u16x8 __attribute__((ext_vector_type(8)));
typedef unsigned short u16x4 __attribute__((ext_vector_type(4)));

#define B_    4
#define N_    4096
#define BN_   16384
#define DM_   1024
#define H_    16
#define BH_   64
#define M_    266
#define MP_   288            // padded feature count (18*16)
#define DN_    0.35355339059327373f   // 64^-0.25
#define RATIO_ 0.061313933948496574f  // 266^-0.5
#define EPS_   1e-4f

static __device__ __forceinline__ float b2f(u16 u) {
    union { u32 u; float f; } x; x.u = ((u32)u) << 16; return x.f;
}
static __device__ __forceinline__ u16 f2b(float f) {
    union { float f; u32 u; } x; x.f = f;
    u32 r = x.u + 0x7FFFu + ((x.u >> 16) & 1u);
    return (u16)(r >> 16);
}
static __device__ __forceinline__ u32 ford(float f) {   // order-preserving uint encode
    u32 u = __float_as_uint(f);
    return (u & 0x80000000u) ? ~u : (u | 0x80000000u);
}
static __device__ __forceinline__ float forddec(u32 u) {
    return (u & 0x80000000u) ? __uint_as_float(u & 0x7FFFFFFFu) : __uint_as_float(~u);
}
static __device__ __forceinline__ f32x4 mfma16(bf16x8 a, bf16x8 b, f32x4 c) {
    return __builtin_amdgcn_mfma_f32_16x16x32_bf16(a, b, c, 0, 0, 0);
}
#define GLOAD16(gp, lp) __builtin_amdgcn_global_load_lds( \
    (const __attribute__((address_space(1))) void*)(gp),  \
    (__attribute__((address_space(3))) void*)(lp), 16, 0, 0)
#define NTST(v, p) __builtin_nontemporal_store((v), (p))
#define NTLD(p)    __builtin_nontemporal_load((p))

// ---------------- merged pack kernel (nt streams) ----------------
__global__ __launch_bounds__(256) void pack_all(const float* __restrict__ x, u16* __restrict__ xb,
                                                const float* __restrict__ Wq, const float* __restrict__ Wk,
                                                const float* __restrict__ Wv, const float* __restrict__ Wo,
                                                u16* __restrict__ wT,
                                                const float* __restrict__ proj, u16* __restrict__ projb,
                                                u32* __restrict__ stabk) {
    __shared__ float tile[64][65];
    int bid = blockIdx.x, tid = threadIdx.x;
    if (bid < 16384) {
        int i = (bid * 256 + tid) * 4;
        f32x4v f = NTLD(reinterpret_cast<const f32x4v*>(x + i));
        u16x4 o;
        o[0] = f2b(f[0]); o[1] = f2b(f[1]); o[2] = f2b(f[2]); o[3] = f2b(f[3]);
        NTST(o, reinterpret_cast<u16x4*>(xb + i));
    } else if (bid < 16384 + 1024) {
        int u = bid - 16384;
        int i0 = (u & 15) * 64;
        int j0 = (u >> 4) * 64;
        const float* src = (j0 < 1024) ? Wq : (j0 < 2048) ? Wk : (j0 < 3072) ? Wv : Wo;
        int jc = j0 & 1023;
        int tr = tid >> 6, tc = tid & 63;
#pragma unroll
        for (int it = 0; it < 16; ++it) {
            int r = it * 4 + tr;
            tile[r][tc] = NTLD(&src[(size_t)(i0 + r) * 1024 + jc + tc]);
        }
        __syncthreads();
#pragma unroll
        for (int it = 0; it < 16; ++it) {
            int r = it * 4 + tr;
            NTST(f2b(tile[tc][r]), &wT[(size_t)(j0 + r) * 1024 + i0 + tc]);
        }
    } else {
        int i = (bid - 17408) * 256 + tid;
        if (i < MP_ * 64) {
            int m = i >> 6;
            projb[i] = (m < M_) ? f2b(proj[i] * DN_) : (u16)0;
        }
        if (i < BH_) stabk[i] = 0u;
    }
}

// ---------------- 256x256 3-phase bf16 MFMA GEMM (T2+T3+T4+T5), K=1024 fixed ----------------
// bf16 output path: acc -> LDS (XOR swizzled) -> u16x8 nontemporal stores (HBM-granule safe).
template<int OUTF32>
__global__ __launch_bounds__(512, 1) void gemm256(const u16* __restrict__ A, const u16* __restrict__ Bt,
                                                  void* __restrict__ C, const float* __restrict__ bias,
                                                  int Ncols, int nby) {
    __shared__ u16 sm[65536];   // [0..32767]: A dbuf; [32768..65535]: B dbuf; reused as C-tile
    constexpr int K = 1024, T = 16;
    int tid = threadIdx.x, lane = tid & 63, wid = tid >> 6;
    int wm = wid >> 2, wn = wid & 3;
    int lr = lane & 15, lk8 = (lane >> 4) * 8;
    int nwg = gridDim.x;
    int wg = ((int)blockIdx.x & 7) * (nwg >> 3) + (int)blockIdx.x / 8;
    int u = wg % (8 * nby), pid = wg / (8 * nby);
    size_t r0 = (size_t)(pid * 8 + (u & 7)) * 256;
    size_t c0 = (size_t)(u / 8) * 256;

    auto stage = [&](int t, int h) {   // h: 0=Ah0 1=Ah1 2=Bh0 3=Bh1
        int buf = t & 1;
        const u16* src = (h < 2) ? (A + r0 * K) : (Bt + c0 * K);
        u16* dst = sm + ((h < 2) ? 0 : 32768) + buf * 16384;
        int rbase = (h & 1) * 128;
        int kt = t * 64;
#pragma unroll
        for (int c = 0; c < 2; ++c) {
            int li0 = rbase * 8 + c * 512 + wid * 64;
            int li = li0 + lane;
            int row = li >> 3, kk = (li & 7) * 8;
            int kks = kk ^ ((row & 7) << 3);
            GLOAD16(&src[(size_t)row * K + kt + kks], (char*)dst + (size_t)li0 * 16);
        }
    };
    auto lda = [&](int buf, int mf, int ks) {
        int row = wm * 128 + mf * 16 + lr;
        return *reinterpret_cast<const bf16x8*>(
            &sm[buf * 16384 + row * 64 + ((ks * 32 + lk8) ^ ((row & 7) << 3))]);
    };
    auto ldb = [&](int buf, int nf, int ks) {
        int row = wn * 64 + nf * 16 + lr;
        return *reinterpret_cast<const bf16x8*>(
            &sm[32768 + buf * 16384 + row * 64 + ((ks * 32 + lk8) ^ ((row & 7) << 3))]);
    };

    f32x4 acc[8][4] = {};
    stage(0, 0); stage(0, 1); stage(0, 2); stage(0, 3);
    stage(1, 2); stage(1, 3); stage(1, 0);
    asm volatile("s_waitcnt vmcnt(6)" ::: "memory");
    __builtin_amdgcn_s_barrier();

#pragma unroll 2
    for (int t = 0; t < T; ++t) {
        const int buf = t & 1;
        bf16x8 av[4][2], aw[4][2], bv[4][2];
#pragma unroll
        for (int mf = 0; mf < 4; ++mf) { av[mf][0] = lda(buf, mf, 0); av[mf][1] = lda(buf, mf, 1); }
#pragma unroll
        for (int nf = 0; nf < 4; ++nf) { bv[nf][0] = ldb(buf, nf, 0); bv[nf][1] = ldb(buf, nf, 1); }
        if (t + 1 < T) stage(t + 1, 1);
        __builtin_amdgcn_s_barrier();
        __builtin_amdgcn_s_setprio(1);
#pragma unroll
        for (int mf = 0; mf < 4; ++mf)
#pragma unroll
            for (int nf = 0; nf < 4; ++nf) {
                acc[mf][nf] = mfma16(av[mf][0], bv[nf][0], acc[mf][nf]);
                acc[mf][nf] = mfma16(av[mf][1], bv[nf][1], acc[mf][nf]);
            }
        __builtin_amdgcn_s_setprio(0);
        __builtin_amdgcn_s_barrier();
#pragma unroll
        for (int mf = 0; mf < 4; ++mf) { aw[mf][0] = lda(buf, 4 + mf, 0); aw[mf][1] = lda(buf, 4 + mf, 1); }
        if (t + 2 < T) stage(t + 2, 2);
        __builtin_amdgcn_s_barrier();
        __builtin_amdgcn_s_setprio(1);
#pragma unroll
        for (int mf = 0; mf < 4; ++mf)
#pragma unroll
            for (int nf = 0; nf < 2; ++nf) {
                acc[4 + mf][nf] = mfma16(aw[mf][0], bv[nf][0], acc[4 + mf][nf]);
                acc[4 + mf][nf] = mfma16(aw[mf][1], bv[nf][1], acc[4 + mf][nf]);
            }
        __builtin_amdgcn_s_setprio(0);
        __builtin_amdgcn_s_barrier();
        if (t + 2 < T) { stage(t + 2, 3); stage(t + 2, 0); }
        __builtin_amdgcn_s_barrier();
        __builtin_amdgcn_s_setprio(1);
#pragma unroll
        for (int mf = 0; mf < 4; ++mf)
#pragma unroll
            for (int nf = 0; nf < 2; ++nf) {
                acc[4 + mf][2 + nf] = mfma16(aw[mf][0], bv[2 + nf][0], acc[4 + mf][2 + nf]);
                acc[4 + mf][2 + nf] = mfma16(aw[mf][1], bv[2 + nf][1], acc[4 + mf][2 + nf]);
            }
        __builtin_amdgcn_s_setprio(0);
        if (t + 2 < T) asm volatile("s_waitcnt vmcnt(6)" ::: "memory");
        else           asm volatile("s_waitcnt vmcnt(0)" ::: "memory");
        __builtin_amdgcn_s_barrier();
    }

    int rq = (lane >> 4) * 4;
    if (OUTF32) {
        // final output: direct f32 nontemporal stores (64B quarter-wave granule)
#pragma unroll
        for (int mf = 0; mf < 8; ++mf)
#pragma unroll
            for (int nf = 0; nf < 4; ++nf) {
                size_t col = c0 + wn * 64 + nf * 16 + lr;
                float bs = bias[col];
#pragma unroll
                for (int r = 0; r < 4; ++r) {
                    size_t row = r0 + wm * 128 + mf * 16 + rq + r;
                    NTST(acc[mf][nf][r] + bs, &reinterpret_cast<float*>(C)[row * Ncols + col]);
                }
            }
    } else {
        // bounce through LDS (free after K-loop's final barrier) -> wide nt stores
#pragma unroll
        for (int mf = 0; mf < 8; ++mf)
#pragma unroll
            for (int nf = 0; nf < 4; ++nf) {
                int cb = (wn * 64 + nf * 16 + lr) * 2;
#pragma unroll
                for (int r = 0; r < 4; ++r) {
                    int row = wm * 128 + mf * 16 + rq + r;
                    *reinterpret_cast<u16*>((char*)sm + row * 512 + (cb ^ ((row & 15) << 4))) =
                        f2b(acc[mf][nf][r]);
                }
            }
        __syncthreads();
        u16* Cu = reinterpret_cast<u16*>(C);
#pragma unroll
        for (int p = 0; p < 16; ++p) {
            int li = p * 512 + tid;          // 256 rows x 32 col-groups
            int row = li >> 5, c8 = li & 31;
            u16x8 v = *reinterpret_cast<const u16x8*>(
                (char*)sm + row * 512 + ((c8 * 16) ^ ((row & 15) << 4)));
            NTST(v, reinterpret_cast<u16x8*>(&Cu[(r0 + row) * (size_t)Ncols + c0 + c8 * 8]));
        }
    }
}

// ---------------- stab_k = max over (n,m) of dash_k, per head ----------------
__global__ __launch_bounds__(256) void dashk_max(const u16* __restrict__ qkv, const u16* __restrict__ projb,
                                                 u32* __restrict__ stabk) {
    __shared__ u16 kt[128 * 64];
    __shared__ float redbuf[4];
    int bh = blockIdx.y, ch = blockIdx.x;
    int b = bh >> 4, h = bh & 15;
    const u16* src = qkv + ((size_t)(b * N_ + ch * 128)) * 3072 + 1024 + h * 64;
    int tid = threadIdx.x;
#pragma unroll
    for (int c = 0; c < 4; ++c) {
        int li = c * 256 + tid;
        int row = li >> 3, kk = (li & 7) * 8;
        *reinterpret_cast<bf16x8*>(&kt[row * 64 + (kk ^ ((row & 7) << 3))]) =
            *reinterpret_cast<const bf16x8*>(&src[(size_t)row * 3072 + kk]);
    }
    __syncthreads();
    int lane = tid & 63, wid = tid >> 6;
    int lr = lane & 15, lk8 = (lane >> 4) * 8;
    float mx = -3.0e38f;
#pragma unroll
    for (int i = 0; i < 2; ++i) {
        int row = wid * 32 + i * 16 + lr;
        bf16x8 a0 = *reinterpret_cast<const bf16x8*>(&kt[row * 64 + (lk8 ^ ((row & 7) << 3))]);
        bf16x8 a1 = *reinterpret_cast<const bf16x8*>(&kt[row * 64 + ((32 + lk8) ^ ((row & 7) << 3))]);
#pragma unroll
        for (int mf = 0; mf < 17; ++mf) {   // m up to 271; mask <266
            f32x4 d = {0.f, 0.f, 0.f, 0.f};
            const u16* pb = projb + (size_t)(mf * 16 + lr) * 64;
            d = mfma16(a0, *reinterpret_cast<const bf16x8*>(pb + lk8), d);
            d = mfma16(a1, *reinterpret_cast<const bf16x8*>(pb + 32 + lk8), d);
            if (mf * 16 + lr < M_)
                mx = fmaxf(mx, fmaxf(fmaxf(d[0], d[1]), fmaxf(d[2], d[3])));
        }
    }
#pragma unroll
    for (int off = 32; off >= 1; off >>= 1) mx = fmaxf(mx, __shfl_xor(mx, off, 64));
    if (lane == 0) redbuf[wid] = mx;
    __syncthreads();
    if (tid == 0) {
        float m = fmaxf(fmaxf(redbuf[0], redbuf[1]), fmaxf(redbuf[2], redbuf[3]));
        atomicMax(&stabk[bh], ford(m));
    }
}

// ---------------- kp = ratio*(exp(dash-diag-stab)+eps); MFMA context & ksum ----------------
__global__ __launch_bounds__(512, 2) void kp_context(const u16* __restrict__ qkv, const u16* __restrict__ projb,
                                                     const u32* __restrict__ stabk,
                                                     float* __restrict__ ctx_part, float* __restrict__ ksum_part) {
    __shared__ u16 kt[2][64 * 64];
    __shared__ u16 vt[2][64 * 64];
    __shared__ u16 kpT[MP_ * 64];
    __shared__ float ksum_s[4][MP_];
    int bh = blockIdx.y, ch = blockIdx.x;   // ch: 0..7, 512 rows each
    int b = bh >> 4, h = bh & 15;
    int tid = threadIdx.x, lane = tid & 63, wid = tid >> 6;
    int grp = wid >> 2, wid4 = wid & 3;
    int lr = lane & 15, lk8 = (lane >> 4) * 8, rq = (lane >> 4) * 4;
    float stab = forddec(stabk[bh]);
    float ksump[9];
#pragma unroll
    for (int i = 0; i < 9; ++i) ksump[i] = 0.f;
    f32x4 acc[9] = {};
    int drow = wid4 * 16 + lr;

    auto stage_kv = [&](int sc, int buf) {
        int n0 = ch * 512 + sc * 64;
        const u16* srck = qkv + ((size_t)(b * N_ + n0)) * 3072 + 1024 + h * 64;
        const u16* srcv = srck + 1024;
        int li0 = wid * 64;
        int li = li0 + lane;
        int row = li >> 3, kk = (li & 7) * 8;
        int kks = kk ^ ((row & 7) << 3);
        GLOAD16(&srck[(size_t)row * 3072 + kks], (char*)kt[buf] + (size_t)li0 * 16);
        GLOAD16(&srcv[(size_t)row * 3072 + kks], (char*)vt[buf] + (size_t)li0 * 16);
    };

    stage_kv(0, 0);
    asm volatile("s_waitcnt vmcnt(0)" ::: "memory");
    for (int sc = 0; sc < 8; ++sc) {
        int buf = sc & 1;
        __builtin_amdgcn_s_barrier();
        if (sc < 7) stage_kv(sc + 1, buf ^ 1);
        {
            int row = wid4 * 16 + lr;
            bf16x8 a0 = *reinterpret_cast<const bf16x8*>(&kt[buf][row * 64 + (lk8 ^ ((row & 7) << 3))]);
            bf16x8 a1 = *reinterpret_cast<const bf16x8*>(&kt[buf][row * 64 + ((32 + lk8) ^ ((row & 7) << 3))]);
            float ss = 0.f;
#pragma unroll
            for (int j = 0; j < 8; ++j) {
                float f0 = (float)a0[j]; ss = fmaf(f0, f0, ss);
                float f1 = (float)a1[j]; ss = fmaf(f1, f1, ss);
            }
            ss += __shfl_xor(ss, 16, 64);
            ss += __shfl_xor(ss, 32, 64);
            float dgk[4];
#pragma unroll
            for (int r = 0; r < 4; ++r) dgk[r] = 0.0625f * __shfl(ss, rq + r, 64);
            int c4 = wid4 * 16 + rq;
#pragma unroll
            for (int mf = 0; mf < 9; ++mf) {
                int mfg = grp * 9 + mf;
                f32x4 d = {0.f, 0.f, 0.f, 0.f};
                const u16* pb = projb + (size_t)(mfg * 16 + lr) * 64;
                d = mfma16(a0, *reinterpret_cast<const bf16x8*>(pb + lk8), d);
                d = mfma16(a1, *reinterpret_cast<const bf16x8*>(pb + 32 + lk8), d);
                int m = mfg * 16 + lr;
                bool real = (m < M_);
                ushort4 o;
                float v0 = real ? RATIO_ * (__expf(d[0] - dgk[0] - stab) + EPS_) : 0.f;
                float v1 = real ? RATIO_ * (__expf(d[1] - dgk[1] - stab) + EPS_) : 0.f;
                float v2 = real ? RATIO_ * (__expf(d[2] - dgk[2] - stab) + EPS_) : 0.f;
                float v3 = real ? RATIO_ * (__expf(d[3] - dgk[3] - stab) + EPS_) : 0.f;
                o.x = f2b(v0); o.y = f2b(v1); o.z = f2b(v2); o.w = f2b(v3);
                ksump[mf] += v0 + v1 + v2 + v3;
                *reinterpret_cast<ushort4*>(&kpT[m * 64 + (c4 ^ ((m & 7) << 3))]) = o;
            }
        }
        asm volatile("s_waitcnt lgkmcnt(0)" ::: "memory");
        __builtin_amdgcn_s_barrier();
        bf16x8 bv[2];
#pragma unroll
        for (int ks = 0; ks < 2; ++ks) {
            union { u16 s[8]; bf16x8 v; } tmp;
#pragma unroll
            for (int j = 0; j < 8; ++j) {
                int n = ks * 32 + lk8 + j;
                tmp.s[j] = vt[buf][n * 64 + ((drow & ~7) ^ ((n & 7) << 3)) + (drow & 7)];
            }
            bv[ks] = tmp.v;
        }
#pragma unroll
        for (int ks = 0; ks < 2; ++ks) {
#pragma unroll
            for (int mf = 0; mf < 9; ++mf) {
                int mrow = (grp * 9 + mf) * 16 + lr;
                bf16x8 av = *reinterpret_cast<const bf16x8*>(
                    &kpT[mrow * 64 + ((ks * 32 + lk8) ^ ((mrow & 7) << 3))]);
                acc[mf] = mfma16(av, bv[ks], acc[mf]);
            }
        }
        if (sc < 7) asm volatile("s_waitcnt vmcnt(0)" ::: "memory");
    }
    size_t basep = ((size_t)ch * BH_ + bh) * MP_;
#pragma unroll
    for (int mf = 0; mf < 9; ++mf) {
#pragma unroll
        for (int r = 0; r < 4; ++r) {
            int m = (grp * 9 + mf) * 16 + rq + r;
            NTST(acc[mf][r], &ctx_part[(basep + m) * 64 + wid4 * 16 + lr]);
        }
    }
#pragma unroll
    for (int mf = 0; mf < 9; ++mf) {
        float v = ksump[mf];
        v += __shfl_xor(v, 16, 64);
        v += __shfl_xor(v, 32, 64);
        if (lane < 16) ksum_s[wid4][(grp * 9 + mf) * 16 + lane] = v;
    }
    __syncthreads();
    for (int t = tid; t < MP_; t += 512)
        NTST(ksum_s[0][t] + ksum_s[1][t] + ksum_s[2][t] + ksum_s[3][t], &ksum_part[basep + t]);
}

// ---------------- merged reduction: ctx partials -> ctx2 (frag order) ; ksum ----------------
__global__ __launch_bounds__(256) void reduce_all(const float* __restrict__ ctx_part,
                                                  const float* __restrict__ ksum_part,
                                                  u16* __restrict__ ctx2, float* __restrict__ ksum) {
    int bid = blockIdx.x, tid = threadIdx.x;
    if (bid < 576) {
        int t = bid * 256 + tid;       // 64bh * 64d * 36mo
        int mo = t % 36;
        int rest = t / 36;
        int d = rest & 63;
        int bh = rest >> 6;
        u16x8 o;
#pragma unroll
        for (int mm = 0; mm < 8; ++mm) {
            int m = mo * 8 + mm;
            float s = 0.f;
#pragma unroll
            for (int c = 0; c < 8; ++c)
                s += NTLD(&ctx_part[(((size_t)c * BH_ + bh) * MP_ + m) * 64 + d]);
            o[mm] = f2b(s);
        }
        size_t idx = ((((size_t)bh * 4 + (d >> 4)) * 9 + (mo >> 2)) * 64
                      + (mo & 3) * 16 + (d & 15)) * 8;
        NTST(o, reinterpret_cast<u16x8*>(ctx2 + idx));
    } else {
        int t = (bid - 576) * 256 + tid;   // BH_*MP_
        float s = 0.f;
#pragma unroll
        for (int c = 0; c < 8; ++c) s += NTLD(&ksum_part[(size_t)c * BH_ * MP_ + t]);
        NTST(s, &ksum[t]);
    }
}

// ---------------- qp, denom, out = (qp@ctx)*dinv ; 2 chunks/block + q reg-prefetch ----------------
__global__ __launch_bounds__(256) void qp_out(const u16* __restrict__ qkv, const u16* __restrict__ projb,
                                              const float* __restrict__ ksum,
                                              const u16* __restrict__ ctx2, u16* __restrict__ attn) {
    __shared__ u16 qt[64 * 64];
    __shared__ u16 qp_s[64 * 296];
    int bh = blockIdx.y, ch = blockIdx.x;    // ch: 0..31, 128 rows each (2 chunks)
    int b = bh >> 4, h = bh & 15;
    int tid = threadIdx.x, lane = tid & 63, wid = tid >> 6;
    int lr = lane & 15, lk8 = (lane >> 4) * 8, rq = (lane >> 4) * 4;
    float ksh[18];
#pragma unroll
    for (int mf = 0; mf < 18; ++mf) ksh[mf] = ksum[bh * MP_ + mf * 16 + lr];
    const u16* srcq = qkv + ((size_t)(b * N_ + ch * 128)) * 3072 + h * 64;
    int srow = tid >> 2, skk = (tid & 3) * 16;
    int ssw = (srow & 7) << 3;
    int sd0 = srow * 64 + (skk ^ ssw);
    int sd1 = srow * 64 + ((skk + 8) ^ ssw);
    {
        u16x8 qa = *reinterpret_cast<const u16x8*>(&srcq[(size_t)srow * 3072 + skk]);
        u16x8 qb = *reinterpret_cast<const u16x8*>(&srcq[(size_t)srow * 3072 + skk + 8]);
        *reinterpret_cast<u16x8*>(&qt[sd0]) = qa;
        *reinterpret_cast<u16x8*>(&qt[sd1]) = qb;
    }
    asm volatile("s_waitcnt lgkmcnt(0)" ::: "memory");
    __builtin_amdgcn_s_barrier();
#pragma unroll
    for (int c = 0; c < 2; ++c) {
        int n0 = ch * 128 + c * 64;
        int row = wid * 16 + lr;
        bf16x8 a0 = *reinterpret_cast<const bf16x8*>(&qt[row * 64 + (lk8 ^ ((row & 7) << 3))]);
        bf16x8 a1 = *reinterpret_cast<const bf16x8*>(&qt[row * 64 + ((32 + lk8) ^ ((row & 7) << 3))]);
        u16x8 qa, qb;
        if (c == 0) {
            qa = *reinterpret_cast<const u16x8*>(&srcq[(size_t)(64 + srow) * 3072 + skk]);
            qb = *reinterpret_cast<const u16x8*>(&srcq[(size_t)(64 + srow) * 3072 + skk + 8]);
        }
        float ss = 0.f;
#pragma unroll
        for (int j = 0; j < 8; ++j) {
            float f0 = (float)a0[j]; ss = fmaf(f0, f0, ss);
            float f1 = (float)a1[j]; ss = fmaf(f1, f1, ss);
        }
        ss += __shfl_xor(ss, 16, 64);
        ss += __shfl_xor(ss, 32, 64);
        float dq[4];
#pragma unroll
        for (int r = 0; r < 4; ++r) dq[r] = 0.0625f * __shfl(ss, rq + r, 64);
        f32x4 dall[18];
        float mx[4] = {-3e38f, -3e38f, -3e38f, -3e38f};
#pragma unroll
        for (int mf = 0; mf < 18; ++mf) {
            f32x4 d = {0.f, 0.f, 0.f, 0.f};
            const u16* pb = projb + (size_t)(mf * 16 + lr) * 64;
            d = mfma16(a0, *reinterpret_cast<const bf16x8*>(pb + lk8), d);
            d = mfma16(a1, *reinterpret_cast<const bf16x8*>(pb + 32 + lk8), d);
            dall[mf] = d;
            if (mf * 16 + lr < M_) {
#pragma unroll
                for (int r = 0; r < 4; ++r) mx[r] = fmaxf(mx[r], d[r]);
            }
        }
#pragma unroll
        for (int r = 0; r < 4; ++r) {
#pragma unroll
            for (int off = 1; off < 16; off <<= 1)
                mx[r] = fmaxf(mx[r], __shfl_xor(mx[r], off, 64));
        }
        float den[4] = {0.f, 0.f, 0.f, 0.f};
#pragma unroll
        for (int mf = 0; mf < 18; ++mf) {
            int m = mf * 16 + lr;
            bool real = (m < M_);
#pragma unroll
            for (int r = 0; r < 4; ++r) {
                float qv = real ? RATIO_ * (__expf(dall[mf][r] - dq[r] - mx[r]) + EPS_) : 0.f;
                qp_s[(wid * 16 + rq + r) * 296 + m] = f2b(qv);
                den[r] = fmaf(qv, ksh[mf], den[r]);
            }
        }
        float dinv[4];
#pragma unroll
        for (int r = 0; r < 4; ++r) {
            float s = den[r];
#pragma unroll
            for (int off = 1; off < 16; off <<= 1) s += __shfl_xor(s, off, 64);
            dinv[r] = 1.0f / s;
        }
        __builtin_amdgcn_s_barrier();
        if (c == 0) {
            *reinterpret_cast<u16x8*>(&qt[sd0]) = qa;
            *reinterpret_cast<u16x8*>(&qt[sd1]) = qb;
        }
        bf16x8 aq[9];
#pragma unroll
        for (int ks = 0; ks < 9; ++ks)
            aq[ks] = *reinterpret_cast<const bf16x8*>(&qp_s[(wid * 16 + lr) * 296 + ks * 32 + lk8]);
#pragma unroll
        for (int df = 0; df < 4; ++df) {
            f32x4 o = {0.f, 0.f, 0.f, 0.f};
            const u16* pb = ctx2 + ((((size_t)bh * 4 + df) * 9) * 64 + lane) * 8;
#pragma unroll
            for (int ks = 0; ks < 9; ++ks)
                o = mfma16(aq[ks], *reinterpret_cast<const bf16x8*>(pb + (size_t)ks * 512), o);
#pragma unroll
            for (int r = 0; r < 4; ++r) {
                size_t orow = (size_t)b * N_ + n0 + wid * 16 + rq + r;
                NTST(f2b(o[r] * dinv[r]), &attn[orow * 1024 + h * 64 + df * 16 + lr]);
            }
        }
        if (c == 0) {
            asm volatile("s_waitcnt lgkmcnt(0)" ::: "memory");
            __builtin_amdgcn_s_barrier();
        }
    }
}

// ---------------- launch ----------------
extern "C" void kernel_launch(void* const* d_in, const int* in_sizes, int n_in,
                              void* d_out, int out_size, void* d_ws, size_t ws_size,
                              hipStream_t stream) {
    const float* x    = (const float*)d_in[0];
    const float* Wq   = (const float*)d_in[1];
    const float* Wk   = (const float*)d_in[2];
    const float* Wv   = (const float*)d_in[3];
    const float* Wo   = (const float*)d_in[4];
    const float* bo   = (const float*)d_in[5];
    const float* proj = (const float*)d_in[6];
    char* ws = (char*)d_ws;
    u16*   xb    = (u16*)(ws + 0);            // 33,554,432
    u16*   wT    = (u16*)(ws + 33554432);     //  8,388,608
    u16*   qkv   = (u16*)(ws + 41943040);     // 100,663,296
    u16*   projb = (u16*)(ws + 142606336);    //     36,864
    u32*   stabk = (u32*)(ws + 144740352);    //        256
    float* ksum  = (float*)(ws + 144740608);  //     73,728
    u16*   ctx2  = (u16*)(ws + 144814336);    //  2,359,296
    float* ctxp  = (float*)(ws + 147173632);  // 37,748,736
    float* ksump = (float*)(ws + 184922368);  //    589,824
    u16*   attn  = (u16*)(ws + 185512192);    // 33,554,432  (total ~219 MB)
    float* out   = (float*)d_out;

    pack_all<<<17480, 256, 0, stream>>>(x, xb, Wq, Wk, Wv, Wo, wT, proj, projb, stabk);
    gemm256<0><<<768, 512, 0, stream>>>(xb, wT, (void*)qkv, nullptr, 3072, 12);
    dashk_max<<<dim3(32, 64), 256, 0, stream>>>(qkv, projb, stabk);
    kp_context<<<dim3(8, 64), 512, 0, stream>>>(qkv, projb, stabk, ctxp, ksump);
    reduce_all<<<648, 256, 0, stream>>>(ctxp, ksump, ctx2, ksum);
    qp_out<<<dim3(32, 64), 256, 0, stream>>>(qkv, projb, ksum, ctx2, attn);
    gemm256<1><<<256, 512, 0, stream>>>(attn, wT + 3072 * 1024, (void*)out, bo, 1024, 4);
}

// Round 11
// 435.940 us; speedup vs baseline: 1.1171x; 1.1171x over previous
//
#include <hip/hip_runtime.h>
#include <hip/hip_bf16.h>

typedef unsigned short u16;
typedef unsigned int   u32;
typedef __bf16 bf16x8 __attribute__((ext_vector_type(8)));
typedef float  f32x4  __attribute__((ext_vector_type(4)));
typedef unsigned short u16x8 __attribute__((ext_vector_type(8)));

#define B_    4
#define N_    4096
#define BN_   16384
#define DM_   1024
#define H_    16
#define BH_   64
#define M_    266
#define MP_   288            // padded feature count (18*16)
#define DN_    0.35355339059327373f   // 64^-0.25
#define RATIO_ 0.061313933948496574f  // 266^-0.5
#define EPS_   1e-4f

static __device__ __forceinline__ float b2f(u16 u) {
    union { u32 u; float f; } x; x.u = ((u32)u) << 16; return x.f;
}
static __device__ __forceinline__ u16 f2b(float f) {
    union { float f; u32 u; } x; x.f = f;
    u32 r = x.u + 0x7FFFu + ((x.u >> 16) & 1u);
    return (u16)(r >> 16);
}
static __device__ __forceinline__ u32 ford(float f) {   // order-preserving uint encode
    u32 u = __float_as_uint(f);
    return (u & 0x80000000u) ? ~u : (u | 0x80000000u);
}
static __device__ __forceinline__ float forddec(u32 u) {
    return (u & 0x80000000u) ? __uint_as_float(u & 0x7FFFFFFFu) : __uint_as_float(~u);
}
static __device__ __forceinline__ f32x4 mfma16(bf16x8 a, bf16x8 b, f32x4 c) {
    return __builtin_amdgcn_mfma_f32_16x16x32_bf16(a, b, c, 0, 0, 0);
}
// async global->LDS, 16B per lane; gptr per-lane, LDS dest wave-uniform base (+lane*16 HW)
#define GLOAD16(gp, lp) __builtin_amdgcn_global_load_lds( \
    (const __attribute__((address_space(1))) void*)(gp),  \
    (__attribute__((address_space(3))) void*)(lp), 16, 0, 0)

// ---------------- merged pack kernel ----------------
__global__ __launch_bounds__(256) void pack_all(const float* __restrict__ x, u16* __restrict__ xb,
                                                const float* __restrict__ Wq, const float* __restrict__ Wk,
                                                const float* __restrict__ Wv, const float* __restrict__ Wo,
                                                u16* __restrict__ wT,
                                                const float* __restrict__ proj, u16* __restrict__ projb,
                                                u32* __restrict__ stabk) {
    __shared__ float tile[64][65];
    int bid = blockIdx.x, tid = threadIdx.x;
    if (bid < 16384) {
        int i = (bid * 256 + tid) * 4;
        float4 f = *reinterpret_cast<const float4*>(x + i);
        ushort4 o;
        o.x = f2b(f.x); o.y = f2b(f.y); o.z = f2b(f.z); o.w = f2b(f.w);
        *reinterpret_cast<ushort4*>(xb + i) = o;
    } else if (bid < 16384 + 1024) {
        int u = bid - 16384;
        int i0 = (u & 15) * 64;
        int j0 = (u >> 4) * 64;
        const float* src = (j0 < 1024) ? Wq : (j0 < 2048) ? Wk : (j0 < 3072) ? Wv : Wo;
        int jc = j0 & 1023;
        int tr = tid >> 6, tc = tid & 63;
#pragma unroll
        for (int it = 0; it < 16; ++it) {
            int r = it * 4 + tr;
            tile[r][tc] = src[(size_t)(i0 + r) * 1024 + jc + tc];
        }
        __syncthreads();
#pragma unroll
        for (int it = 0; it < 16; ++it) {
            int r = it * 4 + tr;
            wT[(size_t)(j0 + r) * 1024 + i0 + tc] = f2b(tile[tc][r]);
        }
    } else {
        int i = (bid - 17408) * 256 + tid;
        if (i < MP_ * 64) {
            int m = i >> 6;
            projb[i] = (m < M_) ? f2b(proj[i] * DN_) : (u16)0;
        }
        if (i < BH_) stabk[i] = 0u;
    }
}

// ---------------- 256x256 3-phase bf16 MFMA GEMM (T2+T3+T4+T5), K=1024 fixed ----------------
template<int OUTF32>
__global__ __launch_bounds__(512, 1) void gemm256(const u16* __restrict__ A, const u16* __restrict__ Bt,
                                                  void* __restrict__ C, const float* __restrict__ bias,
                                                  int Ncols, int nby) {
    __shared__ u16 As[2][256 * 64];
    __shared__ u16 Bs[2][256 * 64];
    constexpr int K = 1024, T = 16;
    int tid = threadIdx.x, lane = tid & 63, wid = tid >> 6;
    int wm = wid >> 2, wn = wid & 3;
    int lr = lane & 15, lk8 = (lane >> 4) * 8;
    int nwg = gridDim.x;
    int wg = ((int)blockIdx.x & 7) * (nwg >> 3) + (int)blockIdx.x / 8;
    int u = wg % (8 * nby), pid = wg / (8 * nby);
    size_t r0 = (size_t)(pid * 8 + (u & 7)) * 256;
    size_t c0 = (size_t)(u / 8) * 256;

    auto stage = [&](int t, int h) {   // h: 0=Ah0 1=Ah1 2=Bh0 3=Bh1
        int buf = t & 1;
        const u16* src = (h < 2) ? (A + r0 * K) : (Bt + c0 * K);
        u16* dst = (h < 2) ? As[buf] : Bs[buf];
        int rbase = (h & 1) * 128;
        int kt = t * 64;
#pragma unroll
        for (int c = 0; c < 2; ++c) {
            int li0 = rbase * 8 + c * 512 + wid * 64;
            int li = li0 + lane;
            int row = li >> 3, kk = (li & 7) * 8;
            int kks = kk ^ ((row & 7) << 3);
            GLOAD16(&src[(size_t)row * K + kt + kks], (char*)dst + (size_t)li0 * 16);
        }
    };
    auto lda = [&](int buf, int mf, int ks) {
        int row = wm * 128 + mf * 16 + lr;
        return *reinterpret_cast<const bf16x8*>(&As[buf][row * 64 + ((ks * 32 + lk8) ^ ((row & 7) << 3))]);
    };
    auto ldb = [&](int buf, int nf, int ks) {
        int row = wn * 64 + nf * 16 + lr;
        return *reinterpret_cast<const bf16x8*>(&Bs[buf][row * 64 + ((ks * 32 + lk8) ^ ((row & 7) << 3))]);
    };

    f32x4 acc[8][4] = {};
    stage(0, 0); stage(0, 1); stage(0, 2); stage(0, 3);
    stage(1, 2); stage(1, 3); stage(1, 0);
    asm volatile("s_waitcnt vmcnt(6)" ::: "memory");
    __builtin_amdgcn_s_barrier();

#pragma unroll 2
    for (int t = 0; t < T; ++t) {
        const int buf = t & 1;
        bf16x8 av[4][2], aw[4][2], bv[4][2];
#pragma unroll
        for (int mf = 0; mf < 4; ++mf) { av[mf][0] = lda(buf, mf, 0); av[mf][1] = lda(buf, mf, 1); }
#pragma unroll
        for (int nf = 0; nf < 4; ++nf) { bv[nf][0] = ldb(buf, nf, 0); bv[nf][1] = ldb(buf, nf, 1); }
        if (t + 1 < T) stage(t + 1, 1);
        __builtin_amdgcn_s_barrier();
        __builtin_amdgcn_s_setprio(1);
#pragma unroll
        for (int mf = 0; mf < 4; ++mf)
#pragma unroll
            for (int nf = 0; nf < 4; ++nf) {
                acc[mf][nf] = mfma16(av[mf][0], bv[nf][0], acc[mf][nf]);
                acc[mf][nf] = mfma16(av[mf][1], bv[nf][1], acc[mf][nf]);
            }
        __builtin_amdgcn_s_setprio(0);
        __builtin_amdgcn_s_barrier();
#pragma unroll
        for (int mf = 0; mf < 4; ++mf) { aw[mf][0] = lda(buf, 4 + mf, 0); aw[mf][1] = lda(buf, 4 + mf, 1); }
        if (t + 2 < T) stage(t + 2, 2);
        __builtin_amdgcn_s_barrier();
        __builtin_amdgcn_s_setprio(1);
#pragma unroll
        for (int mf = 0; mf < 4; ++mf)
#pragma unroll
            for (int nf = 0; nf < 2; ++nf) {
                acc[4 + mf][nf] = mfma16(aw[mf][0], bv[nf][0], acc[4 + mf][nf]);
                acc[4 + mf][nf] = mfma16(aw[mf][1], bv[nf][1], acc[4 + mf][nf]);
            }
        __builtin_amdgcn_s_setprio(0);
        __builtin_amdgcn_s_barrier();
        if (t + 2 < T) { stage(t + 2, 3); stage(t + 2, 0); }
        __builtin_amdgcn_s_barrier();
        __builtin_amdgcn_s_setprio(1);
#pragma unroll
        for (int mf = 0; mf < 4; ++mf)
#pragma unroll
            for (int nf = 0; nf < 2; ++nf) {
                acc[4 + mf][2 + nf] = mfma16(aw[mf][0], bv[2 + nf][0], acc[4 + mf][2 + nf]);
                acc[4 + mf][2 + nf] = mfma16(aw[mf][1], bv[2 + nf][1], acc[4 + mf][2 + nf]);
            }
        __builtin_amdgcn_s_setprio(0);
        if (t + 2 < T) asm volatile("s_waitcnt vmcnt(6)" ::: "memory");
        else           asm volatile("s_waitcnt vmcnt(0)" ::: "memory");
        __builtin_amdgcn_s_barrier();
    }

    int rq = (lane >> 4) * 4;
#pragma unroll
    for (int mf = 0; mf < 8; ++mf)
#pragma unroll
        for (int nf = 0; nf < 4; ++nf) {
            size_t col = c0 + wn * 64 + nf * 16 + lr;
#pragma unroll
            for (int r = 0; r < 4; ++r) {
                size_t row = r0 + wm * 128 + mf * 16 + rq + r;
                float v = acc[mf][nf][r];
                if (OUTF32) reinterpret_cast<float*>(C)[row * Ncols + col] = v + bias[col];
                else        reinterpret_cast<u16*>(C)[row * Ncols + col] = f2b(v);
            }
        }
}

// ---------------- stab_k = max over (n,m) of dash_k, per head ----------------
__global__ __launch_bounds__(256) void dashk_max(const u16* __restrict__ qkv, const u16* __restrict__ projb,
                                                 u32* __restrict__ stabk) {
    __shared__ u16 kt[128 * 64];
    __shared__ float redbuf[4];
    int bh = blockIdx.y, ch = blockIdx.x;
    int b = bh >> 4, h = bh & 15;
    const u16* src = qkv + ((size_t)(b * N_ + ch * 128)) * 3072 + 1024 + h * 64;
    int tid = threadIdx.x;
#pragma unroll
    for (int c = 0; c < 4; ++c) {
        int li = c * 256 + tid;
        int row = li >> 3, kk = (li & 7) * 8;
        *reinterpret_cast<bf16x8*>(&kt[row * 64 + (kk ^ ((row & 7) << 3))]) =
            *reinterpret_cast<const bf16x8*>(&src[(size_t)row * 3072 + kk]);
    }
    __syncthreads();
    int lane = tid & 63, wid = tid >> 6;
    int lr = lane & 15, lk8 = (lane >> 4) * 8;
    float mx = -3.0e38f;
#pragma unroll
    for (int i = 0; i < 2; ++i) {
        int row = wid * 32 + i * 16 + lr;
        bf16x8 a0 = *reinterpret_cast<const bf16x8*>(&kt[row * 64 + (lk8 ^ ((row & 7) << 3))]);
        bf16x8 a1 = *reinterpret_cast<const bf16x8*>(&kt[row * 64 + ((32 + lk8) ^ ((row & 7) << 3))]);
#pragma unroll
        for (int mf = 0; mf < 17; ++mf) {   // m up to 271; mask <266
            f32x4 d = {0.f, 0.f, 0.f, 0.f};
            const u16* pb = projb + (size_t)(mf * 16 + lr) * 64;
            d = mfma16(a0, *reinterpret_cast<const bf16x8*>(pb + lk8), d);
            d = mfma16(a1, *reinterpret_cast<const bf16x8*>(pb + 32 + lk8), d);
            if (mf * 16 + lr < M_)
                mx = fmaxf(mx, fmaxf(fmaxf(d[0], d[1]), fmaxf(d[2], d[3])));
        }
    }
#pragma unroll
    for (int off = 32; off >= 1; off >>= 1) mx = fmaxf(mx, __shfl_xor(mx, off, 64));
    if (lane == 0) redbuf[wid] = mx;
    __syncthreads();
    if (tid == 0) {
        float m = fmaxf(fmaxf(redbuf[0], redbuf[1]), fmaxf(redbuf[2], redbuf[3]));
        atomicMax(&stabk[bh], ford(m));
    }
}

// ---------------- kp = ratio*(exp(dash-diag-stab)+eps); MFMA context & ksum ----------------
// 512-thread block: waves 0-3 -> m-tiles 0-8, waves 4-7 -> 9-17; k/v staged ONCE per chunk.
__global__ __launch_bounds__(512, 2) void kp_context(const u16* __restrict__ qkv, const u16* __restrict__ projb,
                                                     const u32* __restrict__ stabk,
                                                     float* __restrict__ ctx_part, float* __restrict__ ksum_part) {
    __shared__ u16 kt[2][64 * 64];
    __shared__ u16 vt[2][64 * 64];
    __shared__ u16 kpT[MP_ * 64];
    __shared__ float ksum_s[4][MP_];
    int bh = blockIdx.y, ch = blockIdx.x;   // ch: 0..7, 512 rows each
    int b = bh >> 4, h = bh & 15;
    int tid = threadIdx.x, lane = tid & 63, wid = tid >> 6;
    int grp = wid >> 2, wid4 = wid & 3;
    int lr = lane & 15, lk8 = (lane >> 4) * 8, rq = (lane >> 4) * 4;
    float stab = forddec(stabk[bh]);
    float ksump[9];
#pragma unroll
    for (int i = 0; i < 9; ++i) ksump[i] = 0.f;
    f32x4 acc[9] = {};
    int drow = wid4 * 16 + lr;

    auto stage_kv = [&](int sc, int buf) {
        int n0 = ch * 512 + sc * 64;
        const u16* srck = qkv + ((size_t)(b * N_ + n0)) * 3072 + 1024 + h * 64;
        const u16* srcv = srck + 1024;
        int li0 = wid * 64;
        int li = li0 + lane;
        int row = li >> 3, kk = (li & 7) * 8;
        int kks = kk ^ ((row & 7) << 3);
        GLOAD16(&srck[(size_t)row * 3072 + kks], (char*)kt[buf] + (size_t)li0 * 16);
        GLOAD16(&srcv[(size_t)row * 3072 + kks], (char*)vt[buf] + (size_t)li0 * 16);
    };

    stage_kv(0, 0);
    asm volatile("s_waitcnt vmcnt(0)" ::: "memory");
    for (int sc = 0; sc < 8; ++sc) {
        int buf = sc & 1;
        __builtin_amdgcn_s_barrier();
        if (sc < 7) stage_kv(sc + 1, buf ^ 1);
        {
            int row = wid4 * 16 + lr;
            bf16x8 a0 = *reinterpret_cast<const bf16x8*>(&kt[buf][row * 64 + (lk8 ^ ((row & 7) << 3))]);
            bf16x8 a1 = *reinterpret_cast<const bf16x8*>(&kt[buf][row * 64 + ((32 + lk8) ^ ((row & 7) << 3))]);
            float ss = 0.f;
#pragma unroll
            for (int j = 0; j < 8; ++j) {
                float f0 = (float)a0[j]; ss = fmaf(f0, f0, ss);
                float f1 = (float)a1[j]; ss = fmaf(f1, f1, ss);
            }
            ss += __shfl_xor(ss, 16, 64);
            ss += __shfl_xor(ss, 32, 64);
            float dgk[4];
#pragma unroll
            for (int r = 0; r < 4; ++r) dgk[r] = 0.0625f * __shfl(ss, rq + r, 64);
            int c4 = wid4 * 16 + rq;
#pragma unroll
            for (int mf = 0; mf < 9; ++mf) {
                int mfg = grp * 9 + mf;
                f32x4 d = {0.f, 0.f, 0.f, 0.f};
                const u16* pb = projb + (size_t)(mfg * 16 + lr) * 64;
                d = mfma16(a0, *reinterpret_cast<const bf16x8*>(pb + lk8), d);
                d = mfma16(a1, *reinterpret_cast<const bf16x8*>(pb + 32 + lk8), d);
                int m = mfg * 16 + lr;
                bool real = (m < M_);
                ushort4 o;
                float v0 = real ? RATIO_ * (__expf(d[0] - dgk[0] - stab) + EPS_) : 0.f;
                float v1 = real ? RATIO_ * (__expf(d[1] - dgk[1] - stab) + EPS_) : 0.f;
                float v2 = real ? RATIO_ * (__expf(d[2] - dgk[2] - stab) + EPS_) : 0.f;
                float v3 = real ? RATIO_ * (__expf(d[3] - dgk[3] - stab) + EPS_) : 0.f;
                o.x = f2b(v0); o.y = f2b(v1); o.z = f2b(v2); o.w = f2b(v3);
                ksump[mf] += v0 + v1 + v2 + v3;
                *reinterpret_cast<ushort4*>(&kpT[m * 64 + (c4 ^ ((m & 7) << 3))]) = o;
            }
        }
        asm volatile("s_waitcnt lgkmcnt(0)" ::: "memory");
        __builtin_amdgcn_s_barrier();
        bf16x8 bv[2];
#pragma unroll
        for (int ks = 0; ks < 2; ++ks) {
            union { u16 s[8]; bf16x8 v; } tmp;
#pragma unroll
            for (int j = 0; j < 8; ++j) {
                int n = ks * 32 + lk8 + j;
                tmp.s[j] = vt[buf][n * 64 + ((drow & ~7) ^ ((n & 7) << 3)) + (drow & 7)];
            }
            bv[ks] = tmp.v;
        }
#pragma unroll
        for (int ks = 0; ks < 2; ++ks) {
#pragma unroll
            for (int mf = 0; mf < 9; ++mf) {
                int mrow = (grp * 9 + mf) * 16 + lr;
                bf16x8 av = *reinterpret_cast<const bf16x8*>(
                    &kpT[mrow * 64 + ((ks * 32 + lk8) ^ ((mrow & 7) << 3))]);
                acc[mf] = mfma16(av, bv[ks], acc[mf]);
            }
        }
        if (sc < 7) asm volatile("s_waitcnt vmcnt(0)" ::: "memory");
    }
    size_t basep = ((size_t)ch * BH_ + bh) * MP_;
#pragma unroll
    for (int mf = 0; mf < 9; ++mf) {
#pragma unroll
        for (int r = 0; r < 4; ++r) {
            int m = (grp * 9 + mf) * 16 + rq + r;
            ctx_part[(basep + m) * 64 + wid4 * 16 + lr] = acc[mf][r];
        }
    }
#pragma unroll
    for (int mf = 0; mf < 9; ++mf) {
        float v = ksump[mf];
        v += __shfl_xor(v, 16, 64);
        v += __shfl_xor(v, 32, 64);
        if (lane < 16) ksum_s[wid4][(grp * 9 + mf) * 16 + lane] = v;
    }
    __syncthreads();
    for (int t = tid; t < MP_; t += 512)
        ksum_part[basep + t] = ksum_s[0][t] + ksum_s[1][t] + ksum_s[2][t] + ksum_s[3][t];
}

// ---------------- merged reduction: ctx partials -> ctx2 (frag order) ; ksum ----------------
__global__ __launch_bounds__(256) void reduce_all(const float* __restrict__ ctx_part,
                                                  const float* __restrict__ ksum_part,
                                                  u16* __restrict__ ctx2, float* __restrict__ ksum) {
    int bid = blockIdx.x, tid = threadIdx.x;
    if (bid < 576) {
        int t = bid * 256 + tid;       // 64bh * 64d * 36mo
        int mo = t % 36;
        int rest = t / 36;
        int d = rest & 63;
        int bh = rest >> 6;
        u16x8 o;
#pragma unroll
        for (int mm = 0; mm < 8; ++mm) {
            int m = mo * 8 + mm;
            float s = 0.f;
#pragma unroll
            for (int c = 0; c < 8; ++c)
                s += ctx_part[(((size_t)c * BH_ + bh) * MP_ + m) * 64 + d];
            o[mm] = f2b(s);
        }
        size_t idx = ((((size_t)bh * 4 + (d >> 4)) * 9 + (mo >> 2)) * 64
                      + (mo & 3) * 16 + (d & 15)) * 8;
        *reinterpret_cast<u16x8*>(ctx2 + idx) = o;
    } else {
        int t = (bid - 576) * 256 + tid;   // BH_*MP_
        float s = 0.f;
#pragma unroll
        for (int c = 0; c < 8; ++c) s += ksum_part[(size_t)c * BH_ * MP_ + t];
        ksum[t] = s;
    }
}

// ---------------- qp, denom, out = (qp@ctx)*dinv ; barrier-free, direct-global q ----------------
// qp_s rows are wave-private (wave wid owns rows wid*16..+15): NO cross-wave LDS -> no barriers.
// q fragments loaded straight from global qkv (16-row x 16B gather, L2-resident; 16KB/block).
// LDS 38KB -> 4 blocks/CU (16 waves/CU), each wave fully independent.
__global__ __launch_bounds__(256) void qp_out(const u16* __restrict__ qkv, const u16* __restrict__ projb,
                                              const float* __restrict__ ksum,
                                              const u16* __restrict__ ctx2, u16* __restrict__ attn) {
    __shared__ u16 qp_s[64 * 296];
    int bh = blockIdx.y, ch = blockIdx.x;    // ch: 0..31, 128 rows each (2 chunks)
    int b = bh >> 4, h = bh & 15;
    int tid = threadIdx.x, lane = tid & 63, wid = tid >> 6;
    int lr = lane & 15, lk8 = (lane >> 4) * 8, rq = (lane >> 4) * 4;
    float ksh[18];
#pragma unroll
    for (int mf = 0; mf < 18; ++mf) ksh[mf] = ksum[bh * MP_ + mf * 16 + lr];
    const u16* srcq = qkv + ((size_t)(b * N_ + ch * 128)) * 3072 + h * 64;
#pragma unroll
    for (int c = 0; c < 2; ++c) {
        int n0 = ch * 128 + c * 64;
        int row = wid * 16 + lr;
        const u16* qrow = srcq + (size_t)(c * 64 + row) * 3072;
        bf16x8 a0 = *reinterpret_cast<const bf16x8*>(qrow + lk8);
        bf16x8 a1 = *reinterpret_cast<const bf16x8*>(qrow + 32 + lk8);
        // fused diag_q
        float ss = 0.f;
#pragma unroll
        for (int j = 0; j < 8; ++j) {
            float f0 = (float)a0[j]; ss = fmaf(f0, f0, ss);
            float f1 = (float)a1[j]; ss = fmaf(f1, f1, ss);
        }
        ss += __shfl_xor(ss, 16, 64);
        ss += __shfl_xor(ss, 32, 64);
        float dq[4];
#pragma unroll
        for (int r = 0; r < 4; ++r) dq[r] = 0.0625f * __shfl(ss, rq + r, 64);
        f32x4 dall[18];
        float mx[4] = {-3e38f, -3e38f, -3e38f, -3e38f};
#pragma unroll
        for (int mf = 0; mf < 18; ++mf) {
            f32x4 d = {0.f, 0.f, 0.f, 0.f};
            const u16* pb = projb + (size_t)(mf * 16 + lr) * 64;
            d = mfma16(a0, *reinterpret_cast<const bf16x8*>(pb + lk8), d);
            d = mfma16(a1, *reinterpret_cast<const bf16x8*>(pb + 32 + lk8), d);
            dall[mf] = d;
            if (mf * 16 + lr < M_) {
#pragma unroll
                for (int r = 0; r < 4; ++r) mx[r] = fmaxf(mx[r], d[r]);
            }
        }
#pragma unroll
        for (int r = 0; r < 4; ++r) {
#pragma unroll
            for (int off = 1; off < 16; off <<= 1)
                mx[r] = fmaxf(mx[r], __shfl_xor(mx[r], off, 64));
        }
        float den[4] = {0.f, 0.f, 0.f, 0.f};
#pragma unroll
        for (int mf = 0; mf < 18; ++mf) {
            int m = mf * 16 + lr;
            bool real = (m < M_);
#pragma unroll
            for (int r = 0; r < 4; ++r) {
                float qv = real ? RATIO_ * (__expf(dall[mf][r] - dq[r] - mx[r]) + EPS_) : 0.f;
                qp_s[(wid * 16 + rq + r) * 296 + m] = f2b(qv);
                den[r] = fmaf(qv, ksh[mf], den[r]);
            }
        }
        float dinv[4];
#pragma unroll
        for (int r = 0; r < 4; ++r) {
            float s = den[r];
#pragma unroll
            for (int off = 1; off < 16; off <<= 1) s += __shfl_xor(s, off, 64);
            dinv[r] = 1.0f / s;
        }
        // PV: qp_s rows are own-wave; compiler's lgkmcnt ordering suffices (no barrier)
        bf16x8 aq[9];
#pragma unroll
        for (int ks = 0; ks < 9; ++ks)
            aq[ks] = *reinterpret_cast<const bf16x8*>(&qp_s[(wid * 16 + lr) * 296 + ks * 32 + lk8]);
#pragma unroll
        for (int df = 0; df < 4; ++df) {
            f32x4 o = {0.f, 0.f, 0.f, 0.f};
            const u16* pb = ctx2 + ((((size_t)bh * 4 + df) * 9) * 64 + lane) * 8;
#pragma unroll
            for (int ks = 0; ks < 9; ++ks)
                o = mfma16(aq[ks], *reinterpret_cast<const bf16x8*>(pb + (size_t)ks * 512), o);
#pragma unroll
            for (int r = 0; r < 4; ++r) {
                size_t orow = (size_t)b * N_ + n0 + wid * 16 + rq + r;
                attn[orow * 1024 + h * 64 + df * 16 + lr] = f2b(o[r] * dinv[r]);
            }
        }
    }
}

// ---------------- launch ----------------
extern "C" void kernel_launch(void* const* d_in, const int* in_sizes, int n_in,
                              void* d_out, int out_size, void* d_ws, size_t ws_size,
                              hipStream_t stream) {
    const float* x    = (const float*)d_in[0];
    const float* Wq   = (const float*)d_in[1];
    const float* Wk   = (const float*)d_in[2];
    const float* Wv   = (const float*)d_in[3];
    const float* Wo   = (const float*)d_in[4];
    const float* bo   = (const float*)d_in[5];
    const float* proj = (const float*)d_in[6];
    char* ws = (char*)d_ws;
    u16*   xb    = (u16*)(ws + 0);            // 33,554,432
    u16*   wT    = (u16*)(ws + 33554432);     //  8,388,608
    u16*   qkv   = (u16*)(ws + 41943040);     // 100,663,296
    u16*   projb = (u16*)(ws + 142606336);    //     36,864
    u32*   stabk = (u32*)(ws + 144740352);    //        256
    float* ksum  = (float*)(ws + 144740608);  //     73,728
    u16*   ctx2  = (u16*)(ws + 144814336);    //  2,359,296
    float* ctxp  = (float*)(ws + 147173632);  // 37,748,736
    float* ksump = (float*)(ws + 184922368);  //    589,824
    u16*   attn  = (u16*)(ws + 185512192);    // 33,554,432  (total ~219 MB)
    float* out   = (float*)d_out;

    pack_all<<<17480, 256, 0, stream>>>(x, xb, Wq, Wk, Wv, Wo, wT, proj, projb, stabk);
    gemm256<0><<<768, 512, 0, stream>>>(xb, wT, (void*)qkv, nullptr, 3072, 12);
    dashk_max<<<dim3(32, 64), 256, 0, stream>>>(qkv, projb, stabk);
    kp_context<<<dim3(8, 64), 512, 0, stream>>>(qkv, projb, stabk, ctxp, ksump);
    reduce_all<<<648, 256, 0, stream>>>(ctxp, ksump, ctx2, ksum);
    qp_out<<<dim3(32, 64), 256, 0, stream>>>(qkv, projb, ksum, ctx2, attn);
    gemm256<1><<<256, 512, 0, stream>>>(attn, wT + 3072 * 1024, (void*)out, bo, 1024, 4);
}

// Round 12
// 404.257 us; speedup vs baseline: 1.2046x; 1.0784x over previous
//
#include <hip/hip_runtime.h>
#include <hip/hip_bf16.h>

typedef unsigned short u16;
typedef unsigned int   u32;
typedef __bf16 bf16x8 __attribute__((ext_vector_type(8)));
typedef float  f32x4  __attribute__((ext_vector_type(4)));
typedef unsigned short u16x8 __attribute__((ext_vector_type(8)));

#define B_    4
#define N_    4096
#define BN_   16384
#define DM_   1024
#define H_    16
#define BH_   64
#define M_    266
#define MP_   288            // padded feature count (18*16)
#define DN_    0.35355339059327373f   // 64^-0.25
#define RATIO_ 0.061313933948496574f  // 266^-0.5
#define EPS_   1e-4f

static __device__ __forceinline__ float b2f(u16 u) {
    union { u32 u; float f; } x; x.u = ((u32)u) << 16; return x.f;
}
static __device__ __forceinline__ u16 f2b(float f) {
    union { float f; u32 u; } x; x.f = f;
    u32 r = x.u + 0x7FFFu + ((x.u >> 16) & 1u);
    return (u16)(r >> 16);
}
static __device__ __forceinline__ u32 ford(float f) {   // order-preserving uint encode
    u32 u = __float_as_uint(f);
    return (u & 0x80000000u) ? ~u : (u | 0x80000000u);
}
static __device__ __forceinline__ float forddec(u32 u) {
    return (u & 0x80000000u) ? __uint_as_float(u & 0x7FFFFFFFu) : __uint_as_float(~u);
}
static __device__ __forceinline__ f32x4 mfma16(bf16x8 a, bf16x8 b, f32x4 c) {
    return __builtin_amdgcn_mfma_f32_16x16x32_bf16(a, b, c, 0, 0, 0);
}
// async global->LDS, 16B per lane; gptr per-lane, LDS dest wave-uniform base (+lane*16 HW)
#define GLOAD16(gp, lp) __builtin_amdgcn_global_load_lds( \
    (const __attribute__((address_space(1))) void*)(gp),  \
    (__attribute__((address_space(3))) void*)(lp), 16, 0, 0)

// ---------------- merged pack kernel ----------------
__global__ __launch_bounds__(256) void pack_all(const float* __restrict__ x, u16* __restrict__ xb,
                                                const float* __restrict__ Wq, const float* __restrict__ Wk,
                                                const float* __restrict__ Wv, const float* __restrict__ Wo,
                                                u16* __restrict__ wT,
                                                const float* __restrict__ proj, u16* __restrict__ projb,
                                                u32* __restrict__ stabk) {
    __shared__ float tile[64][65];
    int bid = blockIdx.x, tid = threadIdx.x;
    if (bid < 16384) {
        int i = (bid * 256 + tid) * 4;
        float4 f = *reinterpret_cast<const float4*>(x + i);
        ushort4 o;
        o.x = f2b(f.x); o.y = f2b(f.y); o.z = f2b(f.z); o.w = f2b(f.w);
        *reinterpret_cast<ushort4*>(xb + i) = o;
    } else if (bid < 16384 + 1024) {
        int u = bid - 16384;
        int i0 = (u & 15) * 64;
        int j0 = (u >> 4) * 64;
        const float* src = (j0 < 1024) ? Wq : (j0 < 2048) ? Wk : (j0 < 3072) ? Wv : Wo;
        int jc = j0 & 1023;
        int tr = tid >> 6, tc = tid & 63;
#pragma unroll
        for (int it = 0; it < 16; ++it) {
            int r = it * 4 + tr;
            tile[r][tc] = src[(size_t)(i0 + r) * 1024 + jc + tc];
        }
        __syncthreads();
#pragma unroll
        for (int it = 0; it < 16; ++it) {
            int r = it * 4 + tr;
            wT[(size_t)(j0 + r) * 1024 + i0 + tc] = f2b(tile[tc][r]);
        }
    } else {
        int i = (bid - 17408) * 256 + tid;
        if (i < MP_ * 64) {
            int m = i >> 6;
            projb[i] = (m < M_) ? f2b(proj[i] * DN_) : (u16)0;
        }
        if (i < BH_) stabk[i] = 0u;
    }
}

// ---------------- 256x256 3-phase bf16 MFMA GEMM (T2+T3+T4+T5), K=1024 fixed ----------------
template<int OUTF32>
__global__ __launch_bounds__(512, 1) void gemm256(const u16* __restrict__ A, const u16* __restrict__ Bt,
                                                  void* __restrict__ C, const float* __restrict__ bias,
                                                  int Ncols, int nby) {
    __shared__ u16 As[2][256 * 64];
    __shared__ u16 Bs[2][256 * 64];
    constexpr int K = 1024, T = 16;
    int tid = threadIdx.x, lane = tid & 63, wid = tid >> 6;
    int wm = wid >> 2, wn = wid & 3;
    int lr = lane & 15, lk8 = (lane >> 4) * 8;
    int nwg = gridDim.x;
    int wg = ((int)blockIdx.x & 7) * (nwg >> 3) + (int)blockIdx.x / 8;
    int u = wg % (8 * nby), pid = wg / (8 * nby);
    size_t r0 = (size_t)(pid * 8 + (u & 7)) * 256;
    size_t c0 = (size_t)(u / 8) * 256;

    auto stage = [&](int t, int h) {   // h: 0=Ah0 1=Ah1 2=Bh0 3=Bh1
        int buf = t & 1;
        const u16* src = (h < 2) ? (A + r0 * K) : (Bt + c0 * K);
        u16* dst = (h < 2) ? As[buf] : Bs[buf];
        int rbase = (h & 1) * 128;
        int kt = t * 64;
#pragma unroll
        for (int c = 0; c < 2; ++c) {
            int li0 = rbase * 8 + c * 512 + wid * 64;
            int li = li0 + lane;
            int row = li >> 3, kk = (li & 7) * 8;
            int kks = kk ^ ((row & 7) << 3);
            GLOAD16(&src[(size_t)row * K + kt + kks], (char*)dst + (size_t)li0 * 16);
        }
    };
    auto lda = [&](int buf, int mf, int ks) {
        int row = wm * 128 + mf * 16 + lr;
        return *reinterpret_cast<const bf16x8*>(&As[buf][row * 64 + ((ks * 32 + lk8) ^ ((row & 7) << 3))]);
    };
    auto ldb = [&](int buf, int nf, int ks) {
        int row = wn * 64 + nf * 16 + lr;
        return *reinterpret_cast<const bf16x8*>(&Bs[buf][row * 64 + ((ks * 32 + lk8) ^ ((row & 7) << 3))]);
    };

    f32x4 acc[8][4] = {};
    stage(0, 0); stage(0, 1); stage(0, 2); stage(0, 3);
    stage(1, 2); stage(1, 3); stage(1, 0);
    asm volatile("s_waitcnt vmcnt(6)" ::: "memory");
    __builtin_amdgcn_s_barrier();

#pragma unroll 2
    for (int t = 0; t < T; ++t) {
        const int buf = t & 1;
        bf16x8 av[4][2], aw[4][2], bv[4][2];
#pragma unroll
        for (int mf = 0; mf < 4; ++mf) { av[mf][0] = lda(buf, mf, 0); av[mf][1] = lda(buf, mf, 1); }
#pragma unroll
        for (int nf = 0; nf < 4; ++nf) { bv[nf][0] = ldb(buf, nf, 0); bv[nf][1] = ldb(buf, nf, 1); }
        if (t + 1 < T) stage(t + 1, 1);
        __builtin_amdgcn_s_barrier();
        __builtin_amdgcn_s_setprio(1);
#pragma unroll
        for (int mf = 0; mf < 4; ++mf)
#pragma unroll
            for (int nf = 0; nf < 4; ++nf) {
                acc[mf][nf] = mfma16(av[mf][0], bv[nf][0], acc[mf][nf]);
                acc[mf][nf] = mfma16(av[mf][1], bv[nf][1], acc[mf][nf]);
            }
        __builtin_amdgcn_s_setprio(0);
        __builtin_amdgcn_s_barrier();
#pragma unroll
        for (int mf = 0; mf < 4; ++mf) { aw[mf][0] = lda(buf, 4 + mf, 0); aw[mf][1] = lda(buf, 4 + mf, 1); }
        if (t + 2 < T) stage(t + 2, 2);
        __builtin_amdgcn_s_barrier();
        __builtin_amdgcn_s_setprio(1);
#pragma unroll
        for (int mf = 0; mf < 4; ++mf)
#pragma unroll
            for (int nf = 0; nf < 2; ++nf) {
                acc[4 + mf][nf] = mfma16(aw[mf][0], bv[nf][0], acc[4 + mf][nf]);
                acc[4 + mf][nf] = mfma16(aw[mf][1], bv[nf][1], acc[4 + mf][nf]);
            }
        __builtin_amdgcn_s_setprio(0);
        __builtin_amdgcn_s_barrier();
        if (t + 2 < T) { stage(t + 2, 3); stage(t + 2, 0); }
        __builtin_amdgcn_s_barrier();
        __builtin_amdgcn_s_setprio(1);
#pragma unroll
        for (int mf = 0; mf < 4; ++mf)
#pragma unroll
            for (int nf = 0; nf < 2; ++nf) {
                acc[4 + mf][2 + nf] = mfma16(aw[mf][0], bv[2 + nf][0], acc[4 + mf][2 + nf]);
                acc[4 + mf][2 + nf] = mfma16(aw[mf][1], bv[2 + nf][1], acc[4 + mf][2 + nf]);
            }
        __builtin_amdgcn_s_setprio(0);
        if (t + 2 < T) asm volatile("s_waitcnt vmcnt(6)" ::: "memory");
        else           asm volatile("s_waitcnt vmcnt(0)" ::: "memory");
        __builtin_amdgcn_s_barrier();
    }

    int rq = (lane >> 4) * 4;
#pragma unroll
    for (int mf = 0; mf < 8; ++mf)
#pragma unroll
        for (int nf = 0; nf < 4; ++nf) {
            size_t col = c0 + wn * 64 + nf * 16 + lr;
#pragma unroll
            for (int r = 0; r < 4; ++r) {
                size_t row = r0 + wm * 128 + mf * 16 + rq + r;
                float v = acc[mf][nf][r];
                if (OUTF32) reinterpret_cast<float*>(C)[row * Ncols + col] = v + bias[col];
                else        reinterpret_cast<u16*>(C)[row * Ncols + col] = f2b(v);
            }
        }
}

// ---------------- stab_k = max over (n,m) of dash_k, per head (batched pb loads) ----------------
__global__ __launch_bounds__(256) void dashk_max(const u16* __restrict__ qkv, const u16* __restrict__ projb,
                                                 u32* __restrict__ stabk) {
    __shared__ u16 kt[128 * 64];
    __shared__ float redbuf[4];
    int bh = blockIdx.y, ch = blockIdx.x;
    int b = bh >> 4, h = bh & 15;
    const u16* src = qkv + ((size_t)(b * N_ + ch * 128)) * 3072 + 1024 + h * 64;
    int tid = threadIdx.x;
#pragma unroll
    for (int c = 0; c < 4; ++c) {
        int li = c * 256 + tid;
        int row = li >> 3, kk = (li & 7) * 8;
        *reinterpret_cast<bf16x8*>(&kt[row * 64 + (kk ^ ((row & 7) << 3))]) =
            *reinterpret_cast<const bf16x8*>(&src[(size_t)row * 3072 + kk]);
    }
    __syncthreads();
    int lane = tid & 63, wid = tid >> 6;
    int lr = lane & 15, lk8 = (lane >> 4) * 8;
    float mx = -3.0e38f;
#pragma unroll
    for (int i = 0; i < 2; ++i) {
        int row = wid * 32 + i * 16 + lr;
        bf16x8 a0 = *reinterpret_cast<const bf16x8*>(&kt[row * 64 + (lk8 ^ ((row & 7) << 3))]);
        bf16x8 a1 = *reinterpret_cast<const bf16x8*>(&kt[row * 64 + ((32 + lk8) ^ ((row & 7) << 3))]);
#pragma unroll
        for (int g = 0; g < 6; ++g) {      // 18 mf (rows>=266 are zero-padded; masked below)
            bf16x8 p0[3], p1[3];
#pragma unroll
            for (int j = 0; j < 3; ++j) {
                const u16* pb = projb + (size_t)((g * 3 + j) * 16 + lr) * 64;
                p0[j] = *reinterpret_cast<const bf16x8*>(pb + lk8);
                p1[j] = *reinterpret_cast<const bf16x8*>(pb + 32 + lk8);
            }
#pragma unroll
            for (int j = 0; j < 3; ++j) {
                f32x4 d = {0.f, 0.f, 0.f, 0.f};
                d = mfma16(a0, p0[j], d);
                d = mfma16(a1, p1[j], d);
                if ((g * 3 + j) * 16 + lr < M_)
                    mx = fmaxf(mx, fmaxf(fmaxf(d[0], d[1]), fmaxf(d[2], d[3])));
            }
        }
    }
#pragma unroll
    for (int off = 32; off >= 1; off >>= 1) mx = fmaxf(mx, __shfl_xor(mx, off, 64));
    if (lane == 0) redbuf[wid] = mx;
    __syncthreads();
    if (tid == 0) {
        float m = fmaxf(fmaxf(redbuf[0], redbuf[1]), fmaxf(redbuf[2], redbuf[3]));
        atomicMax(&stabk[bh], ford(m));
    }
}

// ---------------- kp = ratio*(exp(dash-diag-stab)+eps); MFMA context & ksum ----------------
// 512-thread block; batched (pairs) projb loads in phase A.
__global__ __launch_bounds__(512, 2) void kp_context(const u16* __restrict__ qkv, const u16* __restrict__ projb,
                                                     const u32* __restrict__ stabk,
                                                     float* __restrict__ ctx_part, float* __restrict__ ksum_part) {
    __shared__ u16 kt[2][64 * 64];
    __shared__ u16 vt[2][64 * 64];
    __shared__ u16 kpT[MP_ * 64];
    __shared__ float ksum_s[4][MP_];
    int bh = blockIdx.y, ch = blockIdx.x;   // ch: 0..7, 512 rows each
    int b = bh >> 4, h = bh & 15;
    int tid = threadIdx.x, lane = tid & 63, wid = tid >> 6;
    int grp = wid >> 2, wid4 = wid & 3;
    int lr = lane & 15, lk8 = (lane >> 4) * 8, rq = (lane >> 4) * 4;
    float stab = forddec(stabk[bh]);
    float ksump[9];
#pragma unroll
    for (int i = 0; i < 9; ++i) ksump[i] = 0.f;
    f32x4 acc[9] = {};
    int drow = wid4 * 16 + lr;

    auto stage_kv = [&](int sc, int buf) {
        int n0 = ch * 512 + sc * 64;
        const u16* srck = qkv + ((size_t)(b * N_ + n0)) * 3072 + 1024 + h * 64;
        const u16* srcv = srck + 1024;
        int li0 = wid * 64;
        int li = li0 + lane;
        int row = li >> 3, kk = (li & 7) * 8;
        int kks = kk ^ ((row & 7) << 3);
        GLOAD16(&srck[(size_t)row * 3072 + kks], (char*)kt[buf] + (size_t)li0 * 16);
        GLOAD16(&srcv[(size_t)row * 3072 + kks], (char*)vt[buf] + (size_t)li0 * 16);
    };

    auto expstore = [&](int mf, const f32x4& d, const float* dgk) {
        int mfg = grp * 9 + mf;
        int m = mfg * 16 + lr;
        bool real = (m < M_);
        ushort4 o;
        float v0 = real ? RATIO_ * (__expf(d[0] - dgk[0] - stab) + EPS_) : 0.f;
        float v1 = real ? RATIO_ * (__expf(d[1] - dgk[1] - stab) + EPS_) : 0.f;
        float v2 = real ? RATIO_ * (__expf(d[2] - dgk[2] - stab) + EPS_) : 0.f;
        float v3 = real ? RATIO_ * (__expf(d[3] - dgk[3] - stab) + EPS_) : 0.f;
        o.x = f2b(v0); o.y = f2b(v1); o.z = f2b(v2); o.w = f2b(v3);
        ksump[mf] += v0 + v1 + v2 + v3;
        int c4 = wid4 * 16 + rq;
        *reinterpret_cast<ushort4*>(&kpT[m * 64 + (c4 ^ ((m & 7) << 3))]) = o;
    };

    stage_kv(0, 0);
    asm volatile("s_waitcnt vmcnt(0)" ::: "memory");
    for (int sc = 0; sc < 8; ++sc) {
        int buf = sc & 1;
        __builtin_amdgcn_s_barrier();
        if (sc < 7) stage_kv(sc + 1, buf ^ 1);
        {
            int row = wid4 * 16 + lr;
            bf16x8 a0 = *reinterpret_cast<const bf16x8*>(&kt[buf][row * 64 + (lk8 ^ ((row & 7) << 3))]);
            bf16x8 a1 = *reinterpret_cast<const bf16x8*>(&kt[buf][row * 64 + ((32 + lk8) ^ ((row & 7) << 3))]);
            float ss = 0.f;
#pragma unroll
            for (int j = 0; j < 8; ++j) {
                float f0 = (float)a0[j]; ss = fmaf(f0, f0, ss);
                float f1 = (float)a1[j]; ss = fmaf(f1, f1, ss);
            }
            ss += __shfl_xor(ss, 16, 64);
            ss += __shfl_xor(ss, 32, 64);
            float dgk[4];
#pragma unroll
            for (int r = 0; r < 4; ++r) dgk[r] = 0.0625f * __shfl(ss, rq + r, 64);
            // 4 pairs + 1 tail, projb frags batch-loaded per pair
#pragma unroll
            for (int g = 0; g < 4; ++g) {
                bf16x8 p0[2], p1[2];
#pragma unroll
                for (int j = 0; j < 2; ++j) {
                    int mfg = grp * 9 + g * 2 + j;
                    const u16* pb = projb + (size_t)(mfg * 16 + lr) * 64;
                    p0[j] = *reinterpret_cast<const bf16x8*>(pb + lk8);
                    p1[j] = *reinterpret_cast<const bf16x8*>(pb + 32 + lk8);
                }
#pragma unroll
                for (int j = 0; j < 2; ++j) {
                    f32x4 d = {0.f, 0.f, 0.f, 0.f};
                    d = mfma16(a0, p0[j], d);
                    d = mfma16(a1, p1[j], d);
                    expstore(g * 2 + j, d, dgk);
                }
            }
            {
                const u16* pb = projb + (size_t)((grp * 9 + 8) * 16 + lr) * 64;
                bf16x8 p0 = *reinterpret_cast<const bf16x8*>(pb + lk8);
                bf16x8 p1 = *reinterpret_cast<const bf16x8*>(pb + 32 + lk8);
                f32x4 d = {0.f, 0.f, 0.f, 0.f};
                d = mfma16(a0, p0, d);
                d = mfma16(a1, p1, d);
                expstore(8, d, dgk);
            }
        }
        asm volatile("s_waitcnt lgkmcnt(0)" ::: "memory");
        __builtin_amdgcn_s_barrier();
        bf16x8 bv[2];
#pragma unroll
        for (int ks = 0; ks < 2; ++ks) {
            union { u16 s[8]; bf16x8 v; } tmp;
#pragma unroll
            for (int j = 0; j < 8; ++j) {
                int n = ks * 32 + lk8 + j;
                tmp.s[j] = vt[buf][n * 64 + ((drow & ~7) ^ ((n & 7) << 3)) + (drow & 7)];
            }
            bv[ks] = tmp.v;
        }
#pragma unroll
        for (int ks = 0; ks < 2; ++ks) {
#pragma unroll
            for (int mf = 0; mf < 9; ++mf) {
                int mrow = (grp * 9 + mf) * 16 + lr;
                bf16x8 av = *reinterpret_cast<const bf16x8*>(
                    &kpT[mrow * 64 + ((ks * 32 + lk8) ^ ((mrow & 7) << 3))]);
                acc[mf] = mfma16(av, bv[ks], acc[mf]);
            }
        }
        if (sc < 7) asm volatile("s_waitcnt vmcnt(0)" ::: "memory");
    }
    size_t basep = ((size_t)ch * BH_ + bh) * MP_;
#pragma unroll
    for (int mf = 0; mf < 9; ++mf) {
#pragma unroll
        for (int r = 0; r < 4; ++r) {
            int m = (grp * 9 + mf) * 16 + rq + r;
            ctx_part[(basep + m) * 64 + wid4 * 16 + lr] = acc[mf][r];
        }
    }
#pragma unroll
    for (int mf = 0; mf < 9; ++mf) {
        float v = ksump[mf];
        v += __shfl_xor(v, 16, 64);
        v += __shfl_xor(v, 32, 64);
        if (lane < 16) ksum_s[wid4][(grp * 9 + mf) * 16 + lane] = v;
    }
    __syncthreads();
    for (int t = tid; t < MP_; t += 512)
        ksum_part[basep + t] = ksum_s[0][t] + ksum_s[1][t] + ksum_s[2][t] + ksum_s[3][t];
}

// ---------------- merged reduction: ctx partials -> ctx2 (frag order) ; ksum ----------------
__global__ __launch_bounds__(256) void reduce_all(const float* __restrict__ ctx_part,
                                                  const float* __restrict__ ksum_part,
                                                  u16* __restrict__ ctx2, float* __restrict__ ksum) {
    int bid = blockIdx.x, tid = threadIdx.x;
    if (bid < 576) {
        int t = bid * 256 + tid;       // 64bh * 64d * 36mo
        int mo = t % 36;
        int rest = t / 36;
        int d = rest & 63;
        int bh = rest >> 6;
        u16x8 o;
#pragma unroll
        for (int mm = 0; mm < 8; ++mm) {
            int m = mo * 8 + mm;
            float s = 0.f;
#pragma unroll
            for (int c = 0; c < 8; ++c)
                s += ctx_part[(((size_t)c * BH_ + bh) * MP_ + m) * 64 + d];
            o[mm] = f2b(s);
        }
        size_t idx = ((((size_t)bh * 4 + (d >> 4)) * 9 + (mo >> 2)) * 64
                      + (mo & 3) * 16 + (d & 15)) * 8;
        *reinterpret_cast<u16x8*>(ctx2 + idx) = o;
    } else {
        int t = (bid - 576) * 256 + tid;   // BH_*MP_
        float s = 0.f;
#pragma unroll
        for (int c = 0; c < 8; ++c) s += ksum_part[(size_t)c * BH_ * MP_ + t];
        ksum[t] = s;
    }
}

// ---------------- qp, denom, out = (qp@ctx)*dinv ; qt-staged + batched frag loads ----------------
__global__ __launch_bounds__(256) void qp_out(const u16* __restrict__ qkv, const u16* __restrict__ projb,
                                              const float* __restrict__ ksum,
                                              const u16* __restrict__ ctx2, u16* __restrict__ attn) {
    __shared__ u16 qt[64 * 64];
    __shared__ u16 qp_s[64 * 296];
    int bh = blockIdx.y, ch = blockIdx.x;    // ch: 0..31, 128 rows each (2 chunks)
    int b = bh >> 4, h = bh & 15;
    int tid = threadIdx.x, lane = tid & 63, wid = tid >> 6;
    int lr = lane & 15, lk8 = (lane >> 4) * 8, rq = (lane >> 4) * 4;
    float ksh[18];
#pragma unroll
    for (int mf = 0; mf < 18; ++mf) ksh[mf] = ksum[bh * MP_ + mf * 16 + lr];
    const u16* srcq = qkv + ((size_t)(b * N_ + ch * 128)) * 3072 + h * 64;
    int srow = tid >> 2, skk = (tid & 3) * 16;
    int ssw = (srow & 7) << 3;
    int sd0 = srow * 64 + (skk ^ ssw);
    int sd1 = srow * 64 + ((skk + 8) ^ ssw);
    {
        u16x8 qa = *reinterpret_cast<const u16x8*>(&srcq[(size_t)srow * 3072 + skk]);
        u16x8 qb = *reinterpret_cast<const u16x8*>(&srcq[(size_t)srow * 3072 + skk + 8]);
        *reinterpret_cast<u16x8*>(&qt[sd0]) = qa;
        *reinterpret_cast<u16x8*>(&qt[sd1]) = qb;
    }
    asm volatile("s_waitcnt lgkmcnt(0)" ::: "memory");
    __builtin_amdgcn_s_barrier();
#pragma unroll
    for (int c = 0; c < 2; ++c) {
        int n0 = ch * 128 + c * 64;
        int row = wid * 16 + lr;
        bf16x8 a0 = *reinterpret_cast<const bf16x8*>(&qt[row * 64 + (lk8 ^ ((row & 7) << 3))]);
        bf16x8 a1 = *reinterpret_cast<const bf16x8*>(&qt[row * 64 + ((32 + lk8) ^ ((row & 7) << 3))]);
        u16x8 qa, qb;
        if (c == 0) {
            qa = *reinterpret_cast<const u16x8*>(&srcq[(size_t)(64 + srow) * 3072 + skk]);
            qb = *reinterpret_cast<const u16x8*>(&srcq[(size_t)(64 + srow) * 3072 + skk + 8]);
        }
        float ss = 0.f;
#pragma unroll
        for (int j = 0; j < 8; ++j) {
            float f0 = (float)a0[j]; ss = fmaf(f0, f0, ss);
            float f1 = (float)a1[j]; ss = fmaf(f1, f1, ss);
        }
        ss += __shfl_xor(ss, 16, 64);
        ss += __shfl_xor(ss, 32, 64);
        float dq[4];
#pragma unroll
        for (int r = 0; r < 4; ++r) dq[r] = 0.0625f * __shfl(ss, rq + r, 64);
        f32x4 dall[18];
        float mx[4] = {-3e38f, -3e38f, -3e38f, -3e38f};
        // dash: 6 groups of 3 mf, projb frags batch-loaded per group
#pragma unroll
        for (int g = 0; g < 6; ++g) {
            bf16x8 p0[3], p1[3];
#pragma unroll
            for (int j = 0; j < 3; ++j) {
                const u16* pb = projb + (size_t)((g * 3 + j) * 16 + lr) * 64;
                p0[j] = *reinterpret_cast<const bf16x8*>(pb + lk8);
                p1[j] = *reinterpret_cast<const bf16x8*>(pb + 32 + lk8);
            }
#pragma unroll
            for (int j = 0; j < 3; ++j) {
                int mf = g * 3 + j;
                f32x4 d = {0.f, 0.f, 0.f, 0.f};
                d = mfma16(a0, p0[j], d);
                d = mfma16(a1, p1[j], d);
                dall[mf] = d;
                if (mf * 16 + lr < M_) {
#pragma unroll
                    for (int r = 0; r < 4; ++r) mx[r] = fmaxf(mx[r], d[r]);
                }
            }
        }
#pragma unroll
        for (int r = 0; r < 4; ++r) {
#pragma unroll
            for (int off = 1; off < 16; off <<= 1)
                mx[r] = fmaxf(mx[r], __shfl_xor(mx[r], off, 64));
        }
        float den[4] = {0.f, 0.f, 0.f, 0.f};
#pragma unroll
        for (int mf = 0; mf < 18; ++mf) {
            int m = mf * 16 + lr;
            bool real = (m < M_);
#pragma unroll
            for (int r = 0; r < 4; ++r) {
                float qv = real ? RATIO_ * (__expf(dall[mf][r] - dq[r] - mx[r]) + EPS_) : 0.f;
                qp_s[(wid * 16 + rq + r) * 296 + m] = f2b(qv);
                den[r] = fmaf(qv, ksh[mf], den[r]);
            }
        }
        float dinv[4];
#pragma unroll
        for (int r = 0; r < 4; ++r) {
            float s = den[r];
#pragma unroll
            for (int off = 1; off < 16; off <<= 1) s += __shfl_xor(s, off, 64);
            dinv[r] = 1.0f / s;
        }
        __builtin_amdgcn_s_barrier();
        if (c == 0) {
            *reinterpret_cast<u16x8*>(&qt[sd0]) = qa;
            *reinterpret_cast<u16x8*>(&qt[sd1]) = qb;
        }
        bf16x8 aq[9];
#pragma unroll
        for (int ks = 0; ks < 9; ++ks)
            aq[ks] = *reinterpret_cast<const bf16x8*>(&qp_s[(wid * 16 + lr) * 296 + ks * 32 + lk8]);
#pragma unroll
        for (int df = 0; df < 4; ++df) {
            const u16* pb = ctx2 + ((((size_t)bh * 4 + df) * 9) * 64 + lane) * 8;
            bf16x8 cv[9];
#pragma unroll
            for (int ks = 0; ks < 9; ++ks)
                cv[ks] = *reinterpret_cast<const bf16x8*>(pb + (size_t)ks * 512);
            f32x4 o = {0.f, 0.f, 0.f, 0.f};
#pragma unroll
            for (int ks = 0; ks < 9; ++ks)
                o = mfma16(aq[ks], cv[ks], o);
#pragma unroll
            for (int r = 0; r < 4; ++r) {
                size_t orow = (size_t)b * N_ + n0 + wid * 16 + rq + r;
                attn[orow * 1024 + h * 64 + df * 16 + lr] = f2b(o[r] * dinv[r]);
            }
        }
        if (c == 0) {
            asm volatile("s_waitcnt lgkmcnt(0)" ::: "memory");
            __builtin_amdgcn_s_barrier();
        }
    }
}

// ---------------- launch ----------------
extern "C" void kernel_launch(void* const* d_in, const int* in_sizes, int n_in,
                              void* d_out, int out_size, void* d_ws, size_t ws_size,
                              hipStream_t stream) {
    const float* x    = (const float*)d_in[0];
    const float* Wq   = (const float*)d_in[1];
    const float* Wk   = (const float*)d_in[2];
    const float* Wv   = (const float*)d_in[3];
    const float* Wo   = (const float*)d_in[4];
    const float* bo   = (const float*)d_in[5];
    const float* proj = (const float*)d_in[6];
    char* ws = (char*)d_ws;
    u16*   xb    = (u16*)(ws + 0);            // 33,554,432
    u16*   wT    = (u16*)(ws + 33554432);     //  8,388,608
    u16*   qkv   = (u16*)(ws + 41943040);     // 100,663,296
    u16*   projb = (u16*)(ws + 142606336);    //     36,864
    u32*   stabk = (u32*)(ws + 144740352);    //        256
    float* ksum  = (float*)(ws + 144740608);  //     73,728
    u16*   ctx2  = (u16*)(ws + 144814336);    //  2,359,296
    float* ctxp  = (float*)(ws + 147173632);  // 37,748,736
    float* ksump = (float*)(ws + 184922368);  //    589,824
    u16*   attn  = (u16*)(ws + 185512192);    // 33,554,432  (total ~219 MB)
    float* out   = (float*)d_out;

    pack_all<<<17480, 256, 0, stream>>>(x, xb, Wq, Wk, Wv, Wo, wT, proj, projb, stabk);
    gemm256<0><<<768, 512, 0, stream>>>(xb, wT, (void*)qkv, nullptr, 3072, 12);
    dashk_max<<<dim3(32, 64), 256, 0, stream>>>(qkv, projb, stabk);
    kp_context<<<dim3(8, 64), 512, 0, stream>>>(qkv, projb, stabk, ctxp, ksump);
    reduce_all<<<648, 256, 0, stream>>>(ctxp, ksump, ctx2, ksum);
    qp_out<<<dim3(32, 64), 256, 0, stream>>>(qkv, projb, ksum, ctx2, attn);
    gemm256<1><<<256, 512, 0, stream>>>(attn, wT + 3072 * 1024, (void*)out, bo, 1024, 4);
}